// Round 1
// baseline (87.593 us; speedup 1.0000x reference)
//
#include <hip/hip_runtime.h>

constexpr int B = 64, N = 8732, C = 21, M = 16;
constexpr int BN = B * N;
constexpr int TROW = 1 + 6 * M; // 97

struct Ctl {
  unsigned pnum;        // count of positive targets
  unsigned validCount;  // count of valid targets
  float posCE;          // sum of -logp[cls] over positives
  float bboxNum;        // smooth-L1 numerator
  float negSum;         // sum of -logp0 over selected negatives (below kth key)
  unsigned t1, r1, t2, r2, kth, r3;
};

__device__ __forceinline__ unsigned f2key(float f) {
  unsigned u = __float_as_uint(f);
  return (u & 0x80000000u) ? ~u : (u | 0x80000000u);
}
__device__ __forceinline__ float key2f(unsigned k) {
  unsigned u = (k & 0x80000000u) ? (k ^ 0x80000000u) : ~k;
  return __uint_as_float(u);
}

// ---- targets: pnum, positive CE, bbox smooth-L1 (B*M = 1024 threads) ----
__global__ __launch_bounds__(256) void k_targets(
    const float* __restrict__ conf, const float* __restrict__ bbox,
    const float* __restrict__ target, const float* __restrict__ pred,
    Ctl* __restrict__ ctl) {
  int t = blockIdx.x * 256 + threadIdx.x;
  if (t >= B * M) return;
  int b = t >> 4, m = t & 15;
  const float* tr = target + (size_t)b * TROW;
  int num = (int)tr[0];
  if (m >= num) return;  // invalid
  const float* e = tr + 1 + 6 * m;
  int cls = (int)e[0];
  float tx1 = e[1], ty1 = e[2], tx2 = e[3], ty2 = e[4];
  int k = (int)e[5];

  // bbox loss contribution (bmask = valid)
  float p0 = pred[k * 4 + 0], p1 = pred[k * 4 + 1];
  float p2 = pred[k * 4 + 2], p3 = pred[k * 4 + 3];
  float pw = p2 - p0, ph = p3 - p1;
  float pcx = (p0 + p2) * 0.5f, pcy = (p1 + p3) * 0.5f;
  float tw = tx2 - tx1, th = ty2 - ty1;
  float tcx = (tx1 + tx2) * 0.5f, tcy = (ty1 + ty2) * 0.5f;
  float eb0 = (tcx - pcx) / pw;
  float eb1 = (tcy - pcy) / ph;
  float eb2 = __logf(tw / pw);
  float eb3 = __logf(th / ph);
  const float* bo = bbox + ((size_t)b * N + k) * 4;
  float sl = 0.f;
  float ebv[4] = {eb0, eb1, eb2, eb3};
  for (int j = 0; j < 4; j++) {
    float d = bo[j] - ebv[j];
    float ad = fabsf(d);
    sl += (ad < 1.f) ? 0.5f * d * d : ad - 0.5f;
  }
  atomicAdd(&ctl->bboxNum, sl);
  atomicAdd(&ctl->validCount, 1u);

  if (cls > 0) {
    atomicAdd(&ctl->pnum, 1u);
    const float* x = conf + ((size_t)b * N + k) * C;
    float mx = x[0];
    for (int c = 1; c < C; c++) mx = fmaxf(mx, x[c]);
    float s = 0.f;
    for (int c = 0; c < C; c++) s += __expf(x[c] - mx);
    float lp = x[cls] - mx - __logf(s);
    atomicAdd(&ctl->posCE, -lp);
  }
}

// ---- main: logp0 per anchor, keys + level-1 histogram ----
__global__ __launch_bounds__(256) void k_main(
    const float* __restrict__ conf, const float* __restrict__ target,
    unsigned* __restrict__ keys, unsigned* __restrict__ hist1) {
  __shared__ __align__(16) float srow[256 * C];
  __shared__ unsigned shist[4096];
  __shared__ int sk[M];
  int b = blockIdx.y;
  int n0 = blockIdx.x * 256;
  int tid = threadIdx.x;

  for (int i = tid; i < 4096; i += 256) shist[i] = 0;
  if (tid < M) {
    const float* tr = target + (size_t)b * TROW;
    int num = (int)tr[0];
    int k = (int)tr[1 + 6 * tid + 5];
    sk[tid] = (tid < num) ? k : -1;
  }
  __syncthreads();

  int rows = min(256, N - n0);
  const float* gbase = conf + ((size_t)b * N + n0) * C;
  if (rows == 256) {
    const float4* g4 = (const float4*)gbase;
    float4* s4 = (float4*)srow;
    for (int i = tid; i < 256 * C / 4; i += 256) s4[i] = g4[i];
  } else {
    int nflt = rows * C;
    for (int i = tid; i < nflt; i += 256) srow[i] = gbase[i];
  }
  __syncthreads();

  if (tid < rows) {
    int n = n0 + tid;
    const float* x = srow + tid * C;
    float mx = x[0];
    for (int c = 1; c < C; c++) mx = fmaxf(mx, x[c]);
    float s = 0.f;
    for (int c = 0; c < C; c++) s += __expf(x[c] - mx);
    float logp0 = x[0] - mx - __logf(s);
    bool assigned = false;
    for (int j = 0; j < M; j++) assigned |= (sk[j] == n);
    unsigned key = 0xFFFFFFFFu;
    if (!assigned) {
      key = f2key(logp0);
      atomicAdd(&shist[key >> 20], 1u);
    }
    keys[(size_t)b * N + n] = key;
  }
  __syncthreads();
  for (int i = tid; i < 4096; i += 256) {
    unsigned v = shist[i];
    if (v) atomicAdd(&hist1[i], v);
  }
}

// ---- generic 1-block scan over hist: find bin with cum-inclusive >= rank ----
__global__ __launch_bounds__(256) void k_scan(
    const unsigned* __restrict__ hist, int nbins, Ctl* __restrict__ ctl, int mode) {
  __shared__ unsigned chunk[256];
  int tid = threadIdx.x;
  unsigned rank = (mode == 0) ? 3u * ctl->pnum : (mode == 1 ? ctl->r1 : ctl->r2);
  int per = nbins / 256;
  unsigned s = 0;
  for (int j = 0; j < per; j++) s += hist[tid * per + j];
  chunk[tid] = s;
  __syncthreads();
  for (int off = 1; off < 256; off <<= 1) {
    unsigned add = (tid >= off) ? chunk[tid - off] : 0u;
    __syncthreads();
    chunk[tid] += add;
    __syncthreads();
  }
  unsigned cum = chunk[tid] - s;  // exclusive prefix for this thread's chunk
  for (int j = 0; j < per; j++) {
    int bin = tid * per + j;
    unsigned h = hist[bin];
    if (cum < rank && cum + h >= rank) {
      if (mode == 0) { ctl->t1 = (unsigned)bin; ctl->r1 = rank - cum; }
      else if (mode == 1) { ctl->t2 = (unsigned)bin; ctl->r2 = rank - cum; }
      else {
        ctl->kth = (ctl->t1 << 20) | (ctl->t2 << 8) | (unsigned)bin;
        ctl->r3 = rank - cum;
      }
    }
    cum += h;
  }
}

__global__ __launch_bounds__(256) void k_hist2(
    const unsigned* __restrict__ keys, const Ctl* __restrict__ ctl,
    unsigned* __restrict__ hist2) {
  int idx = blockIdx.x * 256 + threadIdx.x;
  if (idx >= BN) return;
  unsigned key = keys[idx];
  if ((key >> 20) == ctl->t1) atomicAdd(&hist2[(key >> 8) & 0xFFFu], 1u);
}

__global__ __launch_bounds__(256) void k_hist3(
    const unsigned* __restrict__ keys, const Ctl* __restrict__ ctl,
    unsigned* __restrict__ hist3) {
  int idx = blockIdx.x * 256 + threadIdx.x;
  if (idx >= BN) return;
  unsigned key = keys[idx];
  unsigned pre = (ctl->t1 << 12) | ctl->t2;
  if ((key >> 8) == pre) atomicAdd(&hist3[key & 0xFFu], 1u);
}

__global__ __launch_bounds__(256) void k_sum(
    const unsigned* __restrict__ keys, Ctl* __restrict__ ctl) {
  unsigned kth = ctl->kth;
  int idx = blockIdx.x * 256 + threadIdx.x;
  float v = 0.f;
  if (idx < BN) {
    unsigned key = keys[idx];
    if (key < kth) v = -key2f(key);  // ce = -logp0
  }
  // block reduction: 4 waves of 64
  for (int off = 32; off > 0; off >>= 1) v += __shfl_down(v, off, 64);
  __shared__ float red[4];
  int lane = threadIdx.x & 63, w = threadIdx.x >> 6;
  if (lane == 0) red[w] = v;
  __syncthreads();
  if (threadIdx.x == 0) {
    float s = red[0] + red[1] + red[2] + red[3];
    if (s != 0.f) atomicAdd(&ctl->negSum, s);
  }
}

__global__ void k_final(const Ctl* __restrict__ ctl, float* __restrict__ out) {
  unsigned P = ctl->pnum;
  unsigned K = 3u * P;
  float kv = -key2f(ctl->kth);
  float negTotal = ctl->negSum + (float)ctl->r3 * kv;
  unsigned denom = max(P + K, 1u);
  out[0] = (ctl->posCE + negTotal) / (float)denom;
  unsigned denb = max(4u * ctl->validCount, 1u);
  out[1] = ctl->bboxNum / (float)denb;
}

extern "C" void kernel_launch(void* const* d_in, const int* in_sizes, int n_in,
                              void* d_out, int out_size, void* d_ws, size_t ws_size,
                              hipStream_t stream) {
  const float* conf = (const float*)d_in[0];
  const float* bbox = (const float*)d_in[1];
  const float* target = (const float*)d_in[2];
  const float* pred = (const float*)d_in[3];
  float* out = (float*)d_out;

  char* ws = (char*)d_ws;
  unsigned* keys = (unsigned*)ws;
  size_t off = (size_t)BN * 4;
  size_t zbase = off;
  unsigned* hist1 = (unsigned*)(ws + off); off += 4096 * 4;
  unsigned* hist2 = (unsigned*)(ws + off); off += 4096 * 4;
  unsigned* hist3 = (unsigned*)(ws + off); off += 256 * 4;
  Ctl* ctl = (Ctl*)(ws + off); off += sizeof(Ctl);

  hipMemsetAsync(ws + zbase, 0, off - zbase, stream);

  int nblk = (BN + 255) / 256;
  k_targets<<<dim3((B * M + 255) / 256), 256, 0, stream>>>(conf, bbox, target, pred, ctl);
  k_main<<<dim3((N + 255) / 256, B), 256, 0, stream>>>(conf, target, keys, hist1);
  k_scan<<<1, 256, 0, stream>>>(hist1, 4096, ctl, 0);
  k_hist2<<<dim3(nblk), 256, 0, stream>>>(keys, ctl, hist2);
  k_scan<<<1, 256, 0, stream>>>(hist2, 4096, ctl, 1);
  k_hist3<<<dim3(nblk), 256, 0, stream>>>(keys, ctl, hist3);
  k_scan<<<1, 256, 0, stream>>>(hist3, 256, ctl, 2);
  k_sum<<<dim3(nblk), 256, 0, stream>>>(keys, ctl);
  k_final<<<1, 1, 0, stream>>>(ctl, out);
}